// Round 4
// baseline (51670.587 us; speedup 1.0000x reference)
//
#include <hip/hip_runtime.h>
#include <hip/hip_bf16.h>

// GRU decoder, B=64, T=512, IN=512, H=1024, 2 layers.
// Runtime dtype detect: inputs fp32 (expected) or bf16; OUTPUT dtype follows.
// Single persistent kernel, 256 WGs x 256 threads; dataflow sync via monotonic
// device-scope counters (no grid barriers).
// Phase p (0..512): layer0 WGs (0..127) compute h0[p] (p<512) -> h0ring;
//                   layer1 WGs (128..255) compute h1[p-1] (p>=1) -> d_out + h1ring.
// Weights staged to bf16 in ws iff (fp32 mode && ws_size fits) — halves traffic.

typedef __attribute__((ext_vector_type(8))) short short8;
typedef __attribute__((ext_vector_type(4))) float floatx4;

#define KC   256            // K-chunk staged in LDS
#define LDA  (KC + 8)       // padded LDS row stride (bf16 elems)

__device__ __forceinline__ float b2f(unsigned short u) {
  union { unsigned int i; float f; } v; v.i = ((unsigned int)u) << 16; return v.f;
}
__device__ __forceinline__ unsigned short f2b(float f) {
  unsigned int xi = __float_as_uint(f);
  return (unsigned short)((xi + 0x7fffu + ((xi >> 16) & 1u)) >> 16);  // RNE
}
__device__ __forceinline__ short8 cvt8(const float* __restrict__ p) {
  float4 a = *(const float4*)p;
  float4 b = *(const float4*)(p + 4);
  short8 v;
  v[0] = (short)f2b(a.x); v[1] = (short)f2b(a.y);
  v[2] = (short)f2b(a.z); v[3] = (short)f2b(a.w);
  v[4] = (short)f2b(b.x); v[5] = (short)f2b(b.y);
  v[6] = (short)f2b(b.z); v[7] = (short)f2b(b.w);
  return v;
}
// load 8 elems as bf16, from fp32 (cvt) or bf16 (raw) source
__device__ __forceinline__ short8 ld8(const void* base, size_t e, bool f32) {
  return f32 ? cvt8((const float*)base + e)
             : *(const short8*)((const unsigned short*)base + e);
}
__device__ __forceinline__ float lds1(const void* base, size_t e, bool f32) {
  return f32 ? ((const float*)base)[e] : b2f(((const unsigned short*)base)[e]);
}

// Mode detect: weights ~U(-0.031,0.031). If data is bf16, every u32's LOW
// half-word is a weight (|v|<=0.031). If fp32, low 16 bits are random mantissa
// bits -> decode as bf16 with random exponent; P(all 1024 <= 1.0) ~ 2^-1024.
__global__ void detect_mode(const unsigned int* __restrict__ w, int* __restrict__ flag) {
  int bad = 0;
  #pragma unroll
  for (int j = 0; j < 4; ++j) {
    unsigned int u = w[threadIdx.x * 4 + j];
    float f = b2f((unsigned short)(u & 0xFFFFu));
    if (!(fabsf(f) <= 1.0f)) bad = 1;    // large / Inf / NaN -> fp32 evidence
  }
  if (bad) atomicOr(flag, 1);
}

__global__ __launch_bounds__(256)
void cvt_w(const float* __restrict__ src, unsigned short* __restrict__ dst, int n,
           const int* __restrict__ flag) {
  if (*flag == 0) return;                 // bf16 mode: no staging (avoid OOB reads)
  int stride = gridDim.x * 256 * 4;
  for (int i = (blockIdx.x * 256 + threadIdx.x) * 4; i + 3 < n; i += stride) {
    float4 f = *(const float4*)(src + i);
    ushort4 u;
    u.x = f2b(f.x); u.y = f2b(f.y); u.z = f2b(f.z); u.w = f2b(f.w);
    *(ushort4*)(dst + i) = u;
  }
}

__device__ __forceinline__ void wait_ge(int* cnt, int target) {
  if (threadIdx.x == 0) {
    while (__hip_atomic_load(cnt, __ATOMIC_ACQUIRE, __HIP_MEMORY_SCOPE_AGENT) < target)
      __builtin_amdgcn_s_sleep(2);
  }
  __syncthreads();
  __threadfence();
}

__global__ __launch_bounds__(256)
void gru_persist(const void* __restrict__ x,     // [64,512,512]
                 const void* __restrict__ ench,  // [64,1024]
                 const void* __restrict__ Wih0, const void* __restrict__ Whh0,
                 const void* __restrict__ bih0, const void* __restrict__ bhh0,
                 const void* __restrict__ Wih1, const void* __restrict__ Whh1,
                 const void* __restrict__ bih1, const void* __restrict__ bhh1,
                 void* __restrict__ out,         // [64,512,1024] + [64,1024]
                 const unsigned short* __restrict__ wih0s,  // staged bf16 or null
                 const unsigned short* __restrict__ whh0s,
                 const unsigned short* __restrict__ wih1s,
                 const unsigned short* __restrict__ whh1s,
                 int* __restrict__ h0cnt, int* __restrict__ h1cnt,
                 const int* __restrict__ flag,
                 unsigned short* __restrict__ h0ring,   // 4 x 64x1024 bf16
                 unsigned short* __restrict__ h1ring)   // 4 x 64x1024 bf16
{
  __shared__ short Abuf[32 * LDA];
  __shared__ float FB[4 * 32 * 16];       // gate exchange: [r/z/ni/nh][32][16]

  const bool f32 = (__hip_atomic_load((int*)flag, __ATOMIC_RELAXED,
                                      __HIP_MEMORY_SCOPE_AGENT) != 0);
  const bool staged = f32 && (wih0s != nullptr);

  const int tid  = threadIdx.x;
  const int wave = tid >> 6;
  const int lane = tid & 63;
  const int ln   = lane & 15;             // m (A rows) / n (B cols)
  const int lq   = lane >> 4;             // k-quad

  const int wg  = blockIdx.x;
  const bool l0 = (wg < 128);
  const int lw  = l0 ? wg : (wg - 128);
  const int mh  = lw & 1;                 // batch rows 32*mh..+31
  const int jt  = lw >> 1;                // cols 16*jt..+15

  const int KTOT = l0 ? 1536 : 2048;
  const int KSPL = l0 ? 512  : 1024;
  const int KWI  = l0 ? 512  : 1024;

  // weight base + per-wave row offsets (gate = wave; wave3 stages only)
  const void* WI; const void* WH; bool wf32;
  if (staged) { WI = l0 ? (const void*)wih0s : (const void*)wih1s;
                WH = l0 ? (const void*)whh0s : (const void*)whh1s; wf32 = false; }
  else        { WI = l0 ? Wih0 : Wih1; WH = l0 ? Whh0 : Whh1; wf32 = f32; }
  size_t wi_off = 0, wh_off = 0;
  if (wave < 3) {
    int row = wave * 1024 + jt * 16 + ln;
    wi_off = (size_t)row * KWI;
    wh_off = (size_t)row * 1024;
  }
  const void* bi = l0 ? bih0 : bih1;
  const void* bh = l0 ? bhh0 : bhh1;

  for (int p = 0; p <= 512; ++p) {
    if (l0) {
      if (p >= 512) break;
      if (p >= 1) wait_ge(h0cnt, 128 * p);         // h0[p-1] ready
      if (p >= 4) wait_ge(h1cnt, 128 * (p - 3));   // h0ring WAR backpressure
    } else {
      if (p == 0) continue;
      wait_ge(h0cnt, 128 * p);                     // h0[p-1] ready
      if (p >= 2) wait_ge(h1cnt, 128 * (p - 1));   // h1[p-2] ready
    }

    floatx4 accR0 = {0,0,0,0}, accR1 = {0,0,0,0};  // wave0:r wave1:z wave2:n_i
    floatx4 accS0 = {0,0,0,0}, accS1 = {0,0,0,0};  // wave2:n_h

    for (int k0 = 0; k0 < KTOT; k0 += KC) {
      // ---- stage A chunk [32 x KC] into LDS ----
      #pragma unroll
      for (int i = 0; i < 4; ++i) {
        int idx = tid + i * 256;
        int r   = idx >> 5;
        int seg = idx & 31;
        int b   = mh * 32 + r;
        int k   = k0 + seg * 8;
        short8 v;
        if (l0) {
          if (k < 512)       v = ld8(x, ((size_t)b * 512 + (size_t)p) * 512 + k, f32);
          else if (p == 0)   v = ld8(ench, (size_t)b * 1024 + (k - 512), f32);
          else v = *(const short8*)(h0ring + (size_t)((p - 1) & 3) * 65536
                                           + (size_t)b * 1024 + (k - 512));
        } else {
          if (k < 1024) v = *(const short8*)(h0ring + (size_t)((p - 1) & 3) * 65536
                                            + (size_t)b * 1024 + k);
          else if (p == 1)   v = ld8(ench, (size_t)b * 1024 + (k - 1024), f32);
          else v = *(const short8*)(h1ring + (size_t)((p - 2) & 3) * 65536
                                           + (size_t)b * 1024 + (k - 1024));
        }
        *(short8*)&Abuf[r * LDA + seg * 8] = v;
      }
      __syncthreads();

      if (wave < 3) {
        #pragma unroll
        for (int kk = 0; kk < KC / 32; ++kk) {
          int ks = k0 + kk * 32;                    // wave-uniform
          int kf = ks + lq * 8;
          short8 bfrag = (ks < KSPL) ? ld8(WI, wi_off + kf, wf32)
                                     : ld8(WH, wh_off + (kf - KSPL), wf32);
          short8 a0 = *(const short8*)&Abuf[ ln       * LDA + kk * 32 + lq * 8];
          short8 a1 = *(const short8*)&Abuf[(16 + ln) * LDA + kk * 32 + lq * 8];
          if (wave < 2 || ks < KSPL) {
            accR0 = __builtin_amdgcn_mfma_f32_16x16x32_bf16(a0, bfrag, accR0, 0, 0, 0);
            accR1 = __builtin_amdgcn_mfma_f32_16x16x32_bf16(a1, bfrag, accR1, 0, 0, 0);
          } else {
            accS0 = __builtin_amdgcn_mfma_f32_16x16x32_bf16(a0, bfrag, accS0, 0, 0, 0);
            accS1 = __builtin_amdgcn_mfma_f32_16x16x32_bf16(a1, bfrag, accS1, 0, 0, 0);
          }
        }
      }
      __syncthreads();
    }

    // ---- cross-wave gate exchange ----
    if (wave < 3) {
      #pragma unroll
      for (int i = 0; i < 4; ++i) {
        int row0 = lq * 4 + i;                      // C/D: row=quad*4+reg, col=ln
        FB[wave * 512 +  row0       * 16 + ln] = accR0[i];
        FB[wave * 512 + (16 + row0) * 16 + ln] = accR1[i];
        if (wave == 2) {
          FB[3 * 512 +  row0       * 16 + ln] = accS0[i];
          FB[3 * 512 + (16 + row0) * 16 + ln] = accS1[i];
        }
      }
    }
    __syncthreads();

    // ---- fused GRU pointwise + publish (2 cells/thread) ----
    {
      const int c  = tid & 15;
      const int rb = tid >> 4;
      const int jcol = jt * 16 + c;
      const float bir = lds1(bi, jcol, f32),        bhr = lds1(bh, jcol, f32);
      const float biz = lds1(bi, 1024 + jcol, f32), bhz = lds1(bh, 1024 + jcol, f32);
      const float bin_= lds1(bi, 2048 + jcol, f32), bhn = lds1(bh, 2048 + jcol, f32);
      #pragma unroll
      for (int half = 0; half < 2; ++half) {
        int rr = rb + 16 * half;
        int b  = mh * 32 + rr;
        float sr  = FB[0 * 512 + rr * 16 + c];
        float sz  = FB[1 * 512 + rr * 16 + c];
        float sni = FB[2 * 512 + rr * 16 + c];
        float snh = FB[3 * 512 + rr * 16 + c];
        float rg = 1.f / (1.f + __expf(-(sr + bir + bhr)));
        float zg = 1.f / (1.f + __expf(-(sz + biz + bhz)));
        float ng = tanhf(sni + bin_ + rg * (snh + bhn));   // r*(hn + bhh_n) !
        float hp;
        if (l0) hp = (p == 0) ? lds1(ench, (size_t)b * 1024 + jcol, f32)
                              : b2f(h0ring[(size_t)((p - 1) & 3) * 65536
                                           + (size_t)b * 1024 + jcol]);
        else    hp = (p >= 2) ? b2f(h1ring[(size_t)((p - 2) & 3) * 65536
                                           + (size_t)b * 1024 + jcol])
                              : lds1(ench, (size_t)b * 1024 + jcol, f32);
        float hnew = (1.f - zg) * ng + zg * hp;
        unsigned short hb = f2b(hnew);
        if (l0) {
          h0ring[(size_t)(p & 3) * 65536 + (size_t)b * 1024 + jcol] = hb;
        } else {
          size_t oidx = ((size_t)b * 512 + (size_t)(p - 1)) * 1024 + jcol;
          if (f32) ((float*)out)[oidx] = hnew;
          else     ((unsigned short*)out)[oidx] = hb;
          h1ring[(size_t)((p - 1) & 3) * 65536 + (size_t)b * 1024 + jcol] = hb;
          if (p == 512) {
            size_t cidx = 33554432u + (size_t)b * 1024 + jcol;   // final carry h1
            if (f32) ((float*)out)[cidx] = hnew;
            else     ((unsigned short*)out)[cidx] = hb;
          }
        }
      }
    }

    __threadfence();
    __syncthreads();
    if (tid == 0)
      __hip_atomic_fetch_add(l0 ? h0cnt : h1cnt, 1,
                             __ATOMIC_RELEASE, __HIP_MEMORY_SCOPE_AGENT);
  }
}

extern "C" void kernel_launch(void* const* d_in, const int* in_sizes, int n_in,
                              void* d_out, int out_size, void* d_ws, size_t ws_size,
                              hipStream_t stream) {
  char* ws = (char*)d_ws;
  int* h0cnt = (int*)ws;
  int* h1cnt = (int*)(ws + 64);
  int* flag  = (int*)(ws + 128);
  unsigned short* h0ring = (unsigned short*)(ws + 4096);     // 512 KB
  unsigned short* h1ring = (unsigned short*)(ws + 528384);   // 512 KB

  // staged bf16 weights (only if ws fits): 22 MB starting at 1,052,672
  const size_t W0 = 1052672;
  unsigned short *w0s = nullptr, *w1s = nullptr, *w2s = nullptr, *w3s = nullptr;
  bool fits = ws_size >= (W0 + 22020096);
  if (fits) {
    w0s = (unsigned short*)(ws + W0);                 // Wih0b: 3,145,728 B
    w1s = (unsigned short*)(ws + W0 + 3145728);       // Whh0b: 6,291,456 B
    w2s = (unsigned short*)(ws + W0 + 9437184);       // Wih1b: 6,291,456 B
    w3s = (unsigned short*)(ws + W0 + 15728640);      // Whh1b: 6,291,456 B
  }

  hipMemsetAsync(d_ws, 0, 256, stream);               // counters + flag

  hipLaunchKernelGGL(detect_mode, dim3(1), dim3(256), 0, stream,
                     (const unsigned int*)d_in[3], flag);
  if (fits) {
    hipLaunchKernelGGL(cvt_w, dim3(256), dim3(256), 0, stream,
                       (const float*)d_in[3], w0s, 1572864, flag);
    hipLaunchKernelGGL(cvt_w, dim3(256), dim3(256), 0, stream,
                       (const float*)d_in[4], w1s, 3145728, flag);
    hipLaunchKernelGGL(cvt_w, dim3(256), dim3(256), 0, stream,
                       (const float*)d_in[7], w2s, 3145728, flag);
    hipLaunchKernelGGL(cvt_w, dim3(256), dim3(256), 0, stream,
                       (const float*)d_in[8], w3s, 3145728, flag);
  }

  hipLaunchKernelGGL(gru_persist, dim3(256), dim3(256), 0, stream,
                     d_in[0], d_in[2],
                     d_in[3], d_in[4], d_in[5], d_in[6],
                     d_in[7], d_in[8], d_in[9], d_in[10],
                     d_out, w0s, w1s, w2s, w3s,
                     h0cnt, h1cnt, flag, h0ring, h1ring);
}